// Round 11
// baseline (712.329 us; speedup 1.0000x reference)
//
#include <hip/hip_runtime.h>

#define SEQ_LEN 96
#define PRED_LEN 16
#define HIDDEN 64
#define FEAT 7
#define BATCH 512
#define TL (SEQ_LEN + PRED_LEN)   // 112-row sliding timeline
#define XSTR 8                    // f16 slots per row (16 B -> one b128 read)

typedef _Float16 v2h __attribute__((ext_vector_type(2)));
typedef _Float16 v8h __attribute__((ext_vector_type(8)));

#define L2E 1.4426950408889634f

// v_dot2_f32_f16: a.x*b.x + a.y*b.y + c (2 MACs/inst, fp32 accumulate)
#if __has_builtin(__builtin_amdgcn_fdot2)
#define FDOT2(a, b, c) __builtin_amdgcn_fdot2((a), (b), (c), false)
#else
#define FDOT2(a, b, c) fmaf((float)(a)[0], (float)(b)[0], \
                        fmaf((float)(a)[1], (float)(b)[1], (c)))
#endif

// ONE WAVE = ONE BATCH. Lane u owns unit u: all 4 gates, full K=64 (sigma=1).
// Zero cross-lane communication: no reduction, no gate exchange, NO BARRIER in
// the 1536-step recurrence. h lives in LDS (f16); the write (lane u -> h[u])
// and next step's broadcast reads are ordered by the wave-in-order LDS pipe +
// lockstep execution; __builtin_amdgcn_wave_barrier() (zero-cost scheduling
// fence) pins the compiler's ordering. The r7-r10 plateau (~847 cyc/step) was
// barrier rendezvous + DPP reduce chains + split-K bookkeeping -- all serial
// latency, all structurally removed here. Weights f16x2 -> v_dot2_f32_f16; all
// accumulation/state/activations fp32. Grid = 512 one-wave blocks -> 2 waves/CU
// on separate SIMDs, contention-free.
__global__ __launch_bounds__(64)
__attribute__((amdgpu_waves_per_eu(1, 1)))
void lstm_ar_kernel(
    const float* __restrict__ x,     // [B, 96, 7]
    const float* __restrict__ W_ih,  // [256, 7]
    const float* __restrict__ W_hh,  // [256, 64]
    const float* __restrict__ b_ih,  // [256]
    const float* __restrict__ b_hh,  // [256]
    const float* __restrict__ fc_W,  // [7, 64]
    const float* __restrict__ fc_b,  // [7]
    float* __restrict__ out)         // [B, 16, 7]
{
    __shared__ __align__(16) _Float16 xs[TL * XSTR];  // f16 timeline (pad = 0)
    __shared__ __align__(16) _Float16 hs[HIDDEN];     // f16 h (single buffer)
    __shared__ float fcw[FEAT * HIDDEN];
    __shared__ float fcb[FEAT];

    const int u = threadIdx.x;        // lane = hidden unit 0..63
    const int b = blockIdx.x;         // batch element

    // ---- per-lane weights: 4 gates x 64 K-cols as 32 f16x2 each ----
    v2h wh[4][32];
    #pragma unroll
    for (int g = 0; g < 4; ++g) {
        const float* wr = W_hh + (u + (g << 6)) * HIDDEN;
        #pragma unroll
        for (int m = 0; m < 32; ++m) {
            v2h t;
            t[0] = (_Float16)wr[2 * m];
            t[1] = (_Float16)wr[2 * m + 1];
            wh[g][m] = t;
        }
    }
    v2h wix[4][4];                    // x-cols as 4 f16x2 (col 7 -> 0, eats pad)
    #pragma unroll
    for (int g = 0; g < 4; ++g)
        #pragma unroll
        for (int i = 0; i < 4; ++i) {
            int c0 = 2 * i, c1 = 2 * i + 1;
            v2h t;
            t[0] = (_Float16)W_ih[(u + (g << 6)) * FEAT + c0];
            t[1] = (c1 < FEAT) ? (_Float16)W_ih[(u + (g << 6)) * FEAT + c1]
                               : (_Float16)0.0f;
            wix[g][i] = t;
        }
    float bias[4];
    #pragma unroll
    for (int g = 0; g < 4; ++g)
        bias[g] = b_ih[u + (g << 6)] + b_hh[u + (g << 6)];

    // ---- stage timeline (zero-fill incl. pred rows & pads), fc, init ----
    for (int i = u; i < TL * XSTR; i += 64) xs[i] = (_Float16)0.0f;
    for (int i = u; i < SEQ_LEN * FEAT; i += 64) {
        int row = i / FEAT, f = i - row * FEAT;
        xs[row * XSTR + f] = (_Float16)x[b * SEQ_LEN * FEAT + i];
    }
    for (int i = u; i < FEAT * HIDDEN; i += 64) fcw[i] = fc_W[i];
    if (u < FEAT) fcb[u] = fc_b[u];
    hs[u] = (_Float16)0.0f;
    float c = 0.0f;                   // cell state of unit u (in-lane)
    __builtin_amdgcn_wave_barrier();  // pin init before loop (lockstep wave)

    for (int k = 0; k < PRED_LEN; ++k) {
        for (int t = 0; t < SEQ_LEN; ++t) {
            const v8h xv = *(const v8h*)&xs[(k + t) * XSTR];  // broadcast b128
            const v8h* h8 = (const v8h*)hs;

            // 8 accumulator chains (a=even pairs, d=odd pairs) for ILP
            float a0 = bias[0], a1 = bias[1], a2 = bias[2], a3 = bias[3];
            float d0 = 0.0f, d1 = 0.0f, d2 = 0.0f, d3 = 0.0f;

            v2h x01 = __builtin_shufflevector(xv, xv, 0, 1);
            v2h x23 = __builtin_shufflevector(xv, xv, 2, 3);
            v2h x45 = __builtin_shufflevector(xv, xv, 4, 5);
            v2h x67 = __builtin_shufflevector(xv, xv, 6, 7);  // .y = pad 0
            a0 = FDOT2(wix[0][0], x01, a0); d0 = FDOT2(wix[0][1], x23, d0);
            a1 = FDOT2(wix[1][0], x01, a1); d1 = FDOT2(wix[1][1], x23, d1);
            a2 = FDOT2(wix[2][0], x01, a2); d2 = FDOT2(wix[2][1], x23, d2);
            a3 = FDOT2(wix[3][0], x01, a3); d3 = FDOT2(wix[3][1], x23, d3);
            a0 = FDOT2(wix[0][2], x45, a0); d0 = FDOT2(wix[0][3], x67, d0);
            a1 = FDOT2(wix[1][2], x45, a1); d1 = FDOT2(wix[1][3], x67, d1);
            a2 = FDOT2(wix[2][2], x45, a2); d2 = FDOT2(wix[2][3], x67, d2);
            a3 = FDOT2(wix[3][2], x45, a3); d3 = FDOT2(wix[3][3], x67, d3);

            #pragma unroll
            for (int j = 0; j < 8; ++j) {           // 8 broadcast b128 h-reads
                v8h hv = h8[j];
                v2h p0 = __builtin_shufflevector(hv, hv, 0, 1);
                v2h p1 = __builtin_shufflevector(hv, hv, 2, 3);
                v2h p2 = __builtin_shufflevector(hv, hv, 4, 5);
                v2h p3 = __builtin_shufflevector(hv, hv, 6, 7);
                a0 = FDOT2(wh[0][4*j+0], p0, a0);
                a1 = FDOT2(wh[1][4*j+0], p0, a1);
                a2 = FDOT2(wh[2][4*j+0], p0, a2);
                a3 = FDOT2(wh[3][4*j+0], p0, a3);
                d0 = FDOT2(wh[0][4*j+1], p1, d0);
                d1 = FDOT2(wh[1][4*j+1], p1, d1);
                d2 = FDOT2(wh[2][4*j+1], p1, d2);
                d3 = FDOT2(wh[3][4*j+1], p1, d3);
                a0 = FDOT2(wh[0][4*j+2], p2, a0);
                a1 = FDOT2(wh[1][4*j+2], p2, a1);
                a2 = FDOT2(wh[2][4*j+2], p2, a2);
                a3 = FDOT2(wh[3][4*j+2], p2, a3);
                d0 = FDOT2(wh[0][4*j+3], p3, d0);
                d1 = FDOT2(wh[1][4*j+3], p3, d1);
                d2 = FDOT2(wh[2][4*j+3], p3, d2);
                d3 = FDOT2(wh[3][4*j+3], p3, d3);
            }

            float r0 = a0 + d0, r1 = a1 + d1, r2 = a2 + d2, r3 = a3 + d3;

            // in-lane activations (PyTorch order i,f,g,o), exp2+rcp only
            float gi = __builtin_amdgcn_rcpf(
                           1.0f + __builtin_amdgcn_exp2f(r0 * (-L2E)));
            float gf = __builtin_amdgcn_rcpf(
                           1.0f + __builtin_amdgcn_exp2f(r1 * (-L2E)));
            float gg = fmaf(2.0f, __builtin_amdgcn_rcpf(
                           1.0f + __builtin_amdgcn_exp2f(r2 * (-2.0f * L2E))), -1.0f);
            float go = __builtin_amdgcn_rcpf(
                           1.0f + __builtin_amdgcn_exp2f(r3 * (-L2E)));

            c = fmaf(gf, c, gi * gg);
            float th = fmaf(2.0f, __builtin_amdgcn_rcpf(
                           1.0f + __builtin_amdgcn_exp2f(c * (-2.0f * L2E))), -1.0f);
            float h = go * th;

            // reads above precede this write in program order; LDS pipe is
            // in-order within a wave -> next step's reads see the new h.
            __builtin_amdgcn_wave_barrier();
            hs[u] = (_Float16)h;
            __builtin_amdgcn_wave_barrier();
        }

        // ---- prediction head: lanes 0..6 (in-wave, no barrier) ----
        if (u < FEAT) {
            float p0 = fcb[u], p1 = 0.0f, p2 = 0.0f, p3 = 0.0f;
            #pragma unroll
            for (int j = 0; j < HIDDEN; j += 4) {
                p0 = fmaf(fcw[u * HIDDEN + j + 0], (float)hs[j + 0], p0);
                p1 = fmaf(fcw[u * HIDDEN + j + 1], (float)hs[j + 1], p1);
                p2 = fmaf(fcw[u * HIDDEN + j + 2], (float)hs[j + 2], p2);
                p3 = fmaf(fcw[u * HIDDEN + j + 3], (float)hs[j + 3], p3);
            }
            float pred = (p0 + p1) + (p2 + p3);
            out[(b * PRED_LEN + k) * FEAT + u] = pred;
            xs[(SEQ_LEN + k) * XSTR + u] = (_Float16)pred;  // append (pad stays 0)
        }
        __builtin_amdgcn_wave_barrier();
    }
}

extern "C" void kernel_launch(void* const* d_in, const int* in_sizes, int n_in,
                              void* d_out, int out_size, void* d_ws, size_t ws_size,
                              hipStream_t stream) {
    const float* x    = (const float*)d_in[0];
    const float* W_ih = (const float*)d_in[1];
    const float* W_hh = (const float*)d_in[2];
    const float* b_ih = (const float*)d_in[3];
    const float* b_hh = (const float*)d_in[4];
    const float* fc_W = (const float*)d_in[5];
    const float* fc_b = (const float*)d_in[6];
    float* out = (float*)d_out;

    lstm_ar_kernel<<<BATCH, 64, 0, stream>>>(x, W_ih, W_hh, b_ih, b_hh, fc_W, fc_b, out);
}